// Round 7
// baseline (6100.945 us; speedup 1.0000x reference)
//
#include <hip/hip_runtime.h>
#include <hip/hip_cooperative_groups.h>
#include <cmath>

namespace cg = cooperative_groups;

#define BB 8
#define NN 2048
#define CC 512
#define NITER 3
#define MP 516      // f64 matrix row stride (elements)
#define MP4 520     // f32 factor row stride (elements)
#define AUGCOL 512
#define NWG 256
#define NT 512

// workspace layout (units: floats); f64 regions 8B-aligned
static constexpr size_t G_OFF   = 0;                         // f32 [B][3][C][C]
static constexpr size_t G_SZ    = (size_t)BB*3*CC*CC;
static constexpr size_t M64_OFF = G_OFF + G_SZ;              // f64 [B][C][MP]
static constexpr size_t M64_SZF = (size_t)BB*CC*MP*2;
static constexpr size_t F32_OFF = M64_OFF + M64_SZF;         // f32 [B][C][MP4]
static constexpr size_t F32_SZ  = (size_t)BB*CC*MP4;
static constexpr size_t T32_OFF = F32_OFF + F32_SZ;          // f32 scratch
static constexpr size_t DF_OFF  = T32_OFF + F32_SZ;          // f64 [B][C][3]
static constexpr size_t DF_SZF  = (size_t)BB*CC*3*2;
static constexpr size_t LMD_OFF = DF_OFF + DF_SZF;           // f64 [B][C]
static constexpr size_t LMD_SZF = (size_t)BB*CC*2;
static constexpr size_t X0_OFF  = LMD_OFF + LMD_SZF;         // f64 [B][C]
static constexpr size_t X0_SZF  = (size_t)BB*CC*2;
static constexpr size_t R64_OFF = X0_OFF + X0_SZF;           // f64 [B][C]
static constexpr size_t R64_SZF = (size_t)BB*CC*2;
static constexpr size_t PERM_OFF= R64_OFF + R64_SZF;         // int [B][8][C]
static constexpr size_t PERM_SZ = (size_t)BB*8*CC;
static constexpr size_t PART_OFF= PERM_OFF + PERM_SZ;        // f32 [8][B][6144]

// ---------------------------------------------------------------------------
// f32 pivoted elimination step, K compile-time (template-unrolled: every r[]
// index static -- rolled loops around r[] spilled to scratch in R3/R4/R5).
template<int K>
__device__ __forceinline__ void panel_step(float (&r)[64], int& mypos, const bool h,
                                           const int t, float* __restrict__ bufB,
                                           float* __restrict__ wv, int* __restrict__ wi,
                                           int* __restrict__ sh_lw)
{
    const float v = (h && mypos >= K) ? fabsf(r[K]) : -1.0f;
    float vmax = v;
    #pragma unroll
    for (int off = 32; off; off >>= 1){
        const float o = __shfl_xor(vmax, off);
        vmax = fmaxf(vmax, o);
    }
    int idx = (v >= 0.0f && v == vmax) ? t : (1 << 20);
    #pragma unroll
    for (int off = 32; off; off >>= 1){
        const int o = __shfl_xor(idx, off);
        idx = min(idx, o);
    }
    if ((t & 63) == 0){ wv[t>>6] = vmax; wi[t>>6] = idx; }
    __syncthreads();
    float gv = wv[0];
    #pragma unroll
    for (int w = 1; w < 8; ++w) gv = fmaxf(gv, wv[w]);
    int wp = 1 << 20;
    #pragma unroll
    for (int w = 0; w < 8; ++w) if (wv[w] == gv) wp = min(wp, wi[w]);
    if (t == wp){
        *sh_lw = mypos;
        #pragma unroll
        for (int j = K; j < 64; ++j) bufB[j] = r[j];
    }
    __syncthreads();
    const int lw = *sh_lw;
    if (t == wp) mypos = K;
    else if (mypos == K) mypos = lw;
    if (h && mypos > K){
        const float pv = bufB[K];
        const float ml = r[K] / pv;
        r[K] = ml;
        #pragma unroll
        for (int j = K + 1; j < 64; ++j) r[j] = fmaf(-ml, bufB[j], r[j]);
    }
}

template<int K>
__device__ __forceinline__ void panel_rec(float (&r)[64], int& mypos, const bool h,
                                          const int t, float* __restrict__ bufB,
                                          float* __restrict__ wv, int* __restrict__ wi,
                                          int* __restrict__ sh_lw)
{
    if constexpr (K < 64){
        panel_step<K>(r, mypos, h, t, bufB, wv, wi, sh_lw);
        panel_rec<K + 1>(r, mypos, h, t, bufB, wv, wi, sh_lw);
    }
}

// ---------------------------------------------------------------------------
// ONE cooperative kernel replacing ~110 stream dispatches (R6 analysis: no
// dispatch >137us, total 5.1ms -> launch/ramp overhead dominated).
__global__ __launch_bounds__(NT, 2) void k_shake(
    const float* __restrict__ pos, const float* __restrict__ mom,
    const float* __restrict__ mas, const float* __restrict__ dtm,
    const float* __restrict__ jacp, const int* __restrict__ pi,
    const int* __restrict__ pj, const float* __restrict__ d0v,
    float* __restrict__ ws, float* __restrict__ out)
{
    cg::grid_group grid = cg::this_grid();
    const int wg = blockIdx.x, t = threadIdx.x;
    __shared__ alignas(16) float sh[8704];

    float* Gg = ws + G_OFF;

    // ================= phase A: G build + diff0 + lambda=0 =================
    if (wg < BB) ((double*)(ws + LMD_OFF))[wg*CC + t] = 0.0;
    for (int task = wg; task < CC*BB; task += NWG){
        const int c = task & (CC-1), b = task >> 9;
        const int i = pi[c], j = pj[c];
        const double im = 1.0 / (double)mas[b*NN + i];
        const double jm = 1.0 / (double)mas[b*NN + j];
        const float* Ji = jacp + ((size_t)b*CC*NN + i)*3;
        const float* Jj = jacp + ((size_t)b*CC*NN + j)*3;
        const size_t o = (size_t)t*NN*3;
        const size_t gb = ((size_t)(b*3)*CC + c)*CC + t;
        Gg[gb]                   = (float)((double)Ji[o+0]*im - (double)Jj[o+0]*jm);
        Gg[gb + (size_t)CC*CC]   = (float)((double)Ji[o+1]*im - (double)Jj[o+1]*jm);
        Gg[gb + (size_t)2*CC*CC] = (float)((double)Ji[o+2]*im - (double)Jj[o+2]*jm);
        if (t == 0){
            double* df = (double*)(ws + DF_OFF) + ((size_t)b*CC + c)*3;
            for (int d = 0; d < 3; ++d)
                df[d] = (double)pos[((size_t)b*NN+i)*3+d] - (double)pos[((size_t)b*NN+j)*3+d];
        }
    }
    grid.sync();

    for (int it = 0; it < NITER; ++it){
        // ================= build: jac (f64 + f32 copy) + con =================
        {
            double* red = (double*)sh;
            for (int task = wg; task < CC*BB; task += NWG){
                const int c = task & (CC-1), b = task >> 9;
                const double* l = (const double*)(ws + LMD_OFF) + (size_t)b*CC;
                const double dt = (double)dtm[b], dt2 = dt*dt;
                const size_t g0 = ((size_t)(b*3)*CC + c)*CC;
                const double lv = l[t];
                const double ga0 = (double)Gg[g0 + t];
                const double ga1 = (double)Gg[g0 + (size_t)CC*CC + t];
                const double ga2 = (double)Gg[g0 + (size_t)2*CC*CC + t];
                double p0 = ga0*lv, p1 = ga1*lv, p2 = ga2*lv;
                #pragma unroll
                for (int off = 32; off; off >>= 1){
                    p0 += __shfl_xor(p0, off);
                    p1 += __shfl_xor(p1, off);
                    p2 += __shfl_xor(p2, off);
                }
                if ((t & 63) == 0){ const int w = t>>6; red[w*3]=p0; red[w*3+1]=p1; red[w*3+2]=p2; }
                __syncthreads();
                double y0 = 0, y1 = 0, y2 = 0;
                #pragma unroll
                for (int w = 0; w < 8; ++w){ y0 += red[w*3]; y1 += red[w*3+1]; y2 += red[w*3+2]; }
                const double* df = (const double*)(ws + DF_OFF) + ((size_t)b*CC + c)*3;
                const double e0 = df[0] - dt2*y0;
                const double e1 = df[1] - dt2*y1;
                const double e2 = df[2] - dt2*y2;
                const double s = -2.0*dt2;
                const double jv = s*(e0*ga0 + e1*ga1 + e2*ga2);
                double* Mrow = (double*)(ws + M64_OFF) + ((size_t)b*CC + c)*MP;
                float*  Frow = ws + F32_OFF + ((size_t)b*CC + c)*MP4;
                Mrow[t] = jv; Frow[t] = (float)jv;
                if (t == 0){
                    const double con = e0*e0 + e1*e1 + e2*e2 - (double)d0v[c];
                    Mrow[AUGCOL] = con; Frow[AUGCOL] = (float)con;
                }
                __syncthreads();
            }
        }
        grid.sync();

        // ================= blocked LU with partial pivoting =================
        for (int kb = 0; kb < 8; ++kb){
            const int base = kb*64, m = CC - base;
            // ---- panel (one WG per batch) ----
            if (wg < BB){
                const int b = wg;
                float* F = ws + F32_OFF + (size_t)b*CC*MP4;
                float* bufB = sh;
                float* wv   = sh + 64;
                int*   wi   = (int*)(sh + 72);
                int*   slw  = (int*)(sh + 80);
                const bool h = (t < m);
                float r[64];
                if (h){
                    const float* sp = F + (size_t)(base + t)*MP4 + base;
                    #pragma unroll
                    for (int j = 0; j < 64; ++j) r[j] = sp[j];
                }
                int mypos = t;
                __syncthreads();
                panel_rec<0>(r, mypos, h, t, bufB, wv, wi, slw);
                if (h){
                    float* dp = F + (size_t)(base + mypos)*MP4 + base;
                    #pragma unroll
                    for (int j = 0; j < 64; ++j) dp[j] = r[j];
                    ((int*)(ws + PERM_OFF))[(b*8 + kb)*CC + mypos] = t;
                }
            }
            grid.sync();
            // ---- apply: permute rows + TRSM per 64-col stripe ----
            {
                const int ntask = (8 - kb)*8;
                float* LT = sh;          // [64][65]  LT[s][i] = L[i][s]
                float* Bs = sh + 4160;   // [64][65]
                for (int task = wg; task < ntask; task += NWG){
                    const int sx = task >> 3, b = task & 7;
                    const bool isaug = (sx == 7 - kb);
                    const int cs = isaug ? AUGCOL : (kb + 1 + sx)*64;
                    const int W  = isaug ? 1 : 64;
                    float* F = ws + F32_OFF + (size_t)b*CC*MP4;
                    float* T = ws + T32_OFF + (size_t)b*CC*MP4;
                    const int* perm = (const int*)(ws + PERM_OFF) + (b*8 + kb)*CC;
                    for (int idx = t; idx < 4096; idx += NT){
                        const int i = idx >> 6, s = idx & 63;
                        LT[s*65 + i] = F[(size_t)(base+i)*MP4 + base + s];
                    }
                    const int c = t & 63, rg = t >> 6;
                    for (int l = rg; l < 64; l += 8)
                        Bs[l*65 + c] = (c < W) ? F[(size_t)(base + perm[l])*MP4 + cs + c] : 0.f;
                    for (int l = 64 + rg; l < m; l += 8)
                        if (c < W) T[(size_t)(base+l)*MP4 + cs + c] = F[(size_t)(base+perm[l])*MP4 + cs + c];
                    __syncthreads();
                    for (int s = 0; s < 63; ++s){
                        const float bsc = Bs[s*65 + c];
                        #pragma unroll
                        for (int i0 = 0; i0 < 8; ++i0){
                            const int i = i0*8 + rg;
                            if (i > s) Bs[i*65 + c] = fmaf(-LT[s*65 + i], bsc, Bs[i*65 + c]);
                        }
                        __syncthreads();
                    }
                    for (int l = rg; l < 64; l += 8)
                        if (c < W) F[(size_t)(base+l)*MP4 + cs + c] = Bs[l*65 + c];
                    __syncthreads();
                }
            }
            grid.sync();
            // ---- trailing GEMM: F = T - L21*U12 ----
            if (kb < 7){
                const int nrt = 7 - kb;
                const int ntask = nrt*(8 - kb)*8;
                float* LTc = sh;          // [64][66]  LTc[kk][r]
                float* Uc  = sh + 4224;   // [64][68]  Uc[kk][c]
                for (int task = wg; task < ntask; task += NWG){
                    const int b = task & 7, r2 = task >> 3;
                    const int rt = r2 % nrt, sx = r2 / nrt;
                    const bool isaug = (sx == 7 - kb);
                    const int cs = isaug ? AUGCOL : (kb + 1 + sx)*64;
                    const int W  = isaug ? 1 : 64;
                    const int gr0 = base + 64 + rt*64;
                    float* F = ws + F32_OFF + (size_t)b*CC*MP4;
                    float* T = ws + T32_OFF + (size_t)b*CC*MP4;
                    for (int idx = t; idx < 4096; idx += NT){
                        const int r = idx >> 6, kk = idx & 63;
                        LTc[kk*66 + r] = F[(size_t)(gr0+r)*MP4 + base + kk];
                    }
                    for (int idx = t; idx < 4096; idx += NT){
                        const int rr = idx >> 6, cc = idx & 63;
                        Uc[rr*68 + cc] = (cc < W) ? F[(size_t)(base + rr)*MP4 + cs + cc] : 0.f;
                    }
                    __syncthreads();
                    const int r0 = (t >> 4)*2, c0 = (t & 15)*4;
                    float a00=0,a01=0,a02=0,a03=0,a10=0,a11=0,a12=0,a13=0;
                    for (int kk = 0; kk < 64; ++kk){
                        const float2 lv = *(const float2*)&LTc[kk*66 + r0];
                        const float4 uv = *(const float4*)&Uc[kk*68 + c0];
                        a00 = fmaf(lv.x, uv.x, a00); a01 = fmaf(lv.x, uv.y, a01);
                        a02 = fmaf(lv.x, uv.z, a02); a03 = fmaf(lv.x, uv.w, a03);
                        a10 = fmaf(lv.y, uv.x, a10); a11 = fmaf(lv.y, uv.y, a11);
                        a12 = fmaf(lv.y, uv.z, a12); a13 = fmaf(lv.y, uv.w, a13);
                    }
                    const float accs[2][4] = {{a00,a01,a02,a03},{a10,a11,a12,a13}};
                    #pragma unroll
                    for (int i = 0; i < 2; ++i)
                        #pragma unroll
                        for (int j = 0; j < 4; ++j){
                            const int c2 = c0 + j;
                            if (c2 < W){
                                const size_t o = (size_t)(gr0 + r0 + i)*MP4 + cs + c2;
                                F[o] = T[o] - accs[i][j];
                            }
                        }
                    __syncthreads();
                }
            }
            grid.sync();
        }

        // ================= backsub -> x0 =================
        if (wg < BB){
            const int b = wg;
            float* F = ws + F32_OFF + (size_t)b*CC*MP4;
            float* y  = sh;
            float* Ud = sh + 512;   // [64][65]
            y[t] = F[(size_t)t*MP4 + AUGCOL];
            __syncthreads();
            for (int sb = 7; sb >= 0; --sb){
                const int rb = sb*64;
                for (int idx = t; idx < 4096; idx += NT)
                    Ud[(idx>>6)*65 + (idx&63)] = F[(size_t)(rb + (idx>>6))*MP4 + rb + (idx&63)];
                __syncthreads();
                if (t < 64){
                    float yv = y[rb + t];
                    for (int kk = 63; kk >= 0; --kk){
                        float xk = __shfl(yv, kk);
                        xk = xk / Ud[kk*65 + kk];
                        if (t == kk) yv = xk;
                        else if (t < kk) yv = fmaf(-Ud[t*65 + kk], xk, yv);
                    }
                    y[rb + t] = yv;
                }
                __syncthreads();
                for (int r = t; r < rb; r += NT){
                    const float* Fr = F + (size_t)r*MP4 + rb;
                    float sacc = 0.f;
                    for (int j = 0; j < 64; ++j) sacc = fmaf(Fr[j], y[rb + j], sacc);
                    y[r] -= sacc;
                }
                __syncthreads();
            }
            ((double*)(ws + X0_OFF))[b*CC + t] = (double)y[t];
        }
        grid.sync();

        // ================= resid: R64 = con - A64@x0 =================
        {
            double* red = (double*)sh;
            for (int task = wg; task < CC*BB; task += NWG){
                const int c = task & (CC-1), b = task >> 9;
                const double* Mrow = (const double*)(ws + M64_OFF) + ((size_t)b*CC + c)*MP;
                const double* x0 = (const double*)(ws + X0_OFF) + (size_t)b*CC;
                double p = Mrow[t]*x0[t];
                #pragma unroll
                for (int off = 32; off; off >>= 1) p += __shfl_xor(p, off);
                if ((t & 63) == 0) red[t>>6] = p;
                __syncthreads();
                if (t == 0){
                    double sm = 0;
                    #pragma unroll
                    for (int w = 0; w < 8; ++w) sm += red[w];
                    ((double*)(ws + R64_OFF))[b*CC + c] = Mrow[AUGCOL] - sm;
                }
                __syncthreads();
            }
        }
        grid.sync();

        // ================= rsolve: d = U^-1 L^-1 P r;  lmd -= x0 + d =======
        if (wg < BB){
            const int b = wg;
            const float* F = ws + F32_OFF + (size_t)b*CC*MP4;
            float* y  = sh;
            float* Ls = sh + 512;   // [64][65]
            y[t] = (float)((const double*)(ws + R64_OFF))[b*CC + t];
            __syncthreads();
            for (int kb2 = 0; kb2 < 8; ++kb2){
                const int base2 = kb2*64, m2 = CC - base2;
                const int* perm = (const int*)(ws + PERM_OFF) + (b*8 + kb2)*CC;
                float v = 0.f;
                if (t < m2) v = y[base2 + perm[t]];
                __syncthreads();
                if (t < m2) y[base2 + t] = v;
                for (int idx = t; idx < 4096; idx += NT)
                    Ls[(idx>>6)*65 + (idx&63)] = F[(size_t)(base2 + (idx>>6))*MP4 + base2 + (idx&63)];
                __syncthreads();
                if (t < 64){
                    float yv = y[base2 + t];
                    for (int kk = 0; kk < 63; ++kk){
                        const float xk = __shfl(yv, kk);
                        if (t > kk) yv = fmaf(-Ls[t*65 + kk], xk, yv);
                    }
                    y[base2 + t] = yv;
                }
                __syncthreads();
                if (t >= 64 && t < m2){
                    const float* Fr = F + (size_t)(base2 + t)*MP4 + base2;
                    float sacc = 0.f;
                    for (int s = 0; s < 64; ++s) sacc = fmaf(Fr[s], y[base2 + s], sacc);
                    y[base2 + t] -= sacc;
                }
                __syncthreads();
            }
            for (int sb = 7; sb >= 0; --sb){
                const int rb = sb*64;
                for (int idx = t; idx < 4096; idx += NT)
                    Ls[(idx>>6)*65 + (idx&63)] = F[(size_t)(rb + (idx>>6))*MP4 + rb + (idx&63)];
                __syncthreads();
                if (t < 64){
                    float yv = y[rb + t];
                    for (int kk = 63; kk >= 0; --kk){
                        float xk = __shfl(yv, kk);
                        xk = xk / Ls[kk*65 + kk];
                        if (t == kk) yv = xk;
                        else if (t < kk) yv = fmaf(-Ls[t*65 + kk], xk, yv);
                    }
                    y[rb + t] = yv;
                }
                __syncthreads();
                if (t < rb){
                    const float* Fr = F + (size_t)t*MP4 + rb;
                    float sacc = 0.f;
                    for (int j = 0; j < 64; ++j) sacc = fmaf(Fr[j], y[rb + j], sacc);
                    y[t] -= sacc;
                }
                __syncthreads();
            }
            double* l = (double*)(ws + LMD_OFF) + (size_t)b*CC;
            const double nx = ((const double*)(ws + X0_OFF))[b*CC + t] + (double)y[t];
            l[t] -= nx;
        }
        grid.sync();
    }

    // ================= frc: split-K partials of lmd . jacp =================
    {
        double* ld = (double*)sh;
        for (int task = wg; task < 12*8*8; task += NWG){
            const int b = task & 7, kc = (task >> 3) & 7, nb = task >> 6;
            const int nd = nb*NT + t;
            const double* l = (const double*)(ws + LMD_OFF) + (size_t)b*CC + kc*64;
            if (t < 64) ld[t] = l[t];
            __syncthreads();
            const float* J = jacp + ((size_t)(b*CC + kc*64))*NN*3 + nd;
            double acc = 0.0;
            for (int c2 = 0; c2 < 64; ++c2) acc = fma(ld[c2], (double)J[(size_t)c2*NN*3], acc);
            ws[PART_OFF + ((size_t)kc*8 + b)*6144 + nd] = (float)acc;
            __syncthreads();
        }
    }
    grid.sync();

    // ================= out =================
    {
        const int idx = wg*NT + t;
        if (idx < BB*6144){
            const int b = idx / 6144, nd = idx % 6144;
            float sacc = 0.f;
            for (int kc = 0; kc < 8; ++kc) sacc += ws[PART_OFF + ((size_t)kc*8 + b)*6144 + nd];
            const float frc = -sacc;
            const int n = nd / 3;
            const float dt = dtm[b], dt2 = dt*dt;
            out[(size_t)b*6144 + nd]         = pos[(size_t)b*6144 + nd] + frc / mas[b*NN + n] * dt2;
            out[49152 + (size_t)b*6144 + nd] = mom[(size_t)b*6144 + nd] + frc * dt;
        } else if (idx < BB*6144 + BB*CC){
            const int k = idx - BB*6144;
            out[98304 + k] = (float)(((const double*)(ws + LMD_OFF))[k]);
        }
    }
}

// ---------------------------------------------------------------------------
extern "C" void kernel_launch(void* const* d_in, const int* in_sizes, int n_in,
                              void* d_out, int out_size, void* d_ws, size_t ws_size,
                              hipStream_t stream)
{
    (void)in_sizes; (void)n_in; (void)out_size; (void)ws_size;
    const float* pos  = (const float*)d_in[0];
    const float* mom  = (const float*)d_in[1];
    const float* mas  = (const float*)d_in[2];
    const float* dtm  = (const float*)d_in[3];
    const float* jacp = (const float*)d_in[4];
    const int*   pi   = (const int*)d_in[5];
    const int*   pj   = (const int*)d_in[6];
    const float* d0v  = (const float*)d_in[7];
    float* ws  = (float*)d_ws;
    float* out = (float*)d_out;
    void* args[] = {(void*)&pos, (void*)&mom, (void*)&mas, (void*)&dtm, (void*)&jacp,
                    (void*)&pi, (void*)&pj, (void*)&d0v, (void*)&ws, (void*)&out};
    hipLaunchCooperativeKernel((const void*)k_shake, dim3(NWG), dim3(NT), args, 0, stream);
}